// Round 10
// baseline (91.772 us; speedup 1.0000x reference)
//
#include <hip/hip_runtime.h>

typedef unsigned long long u64;

#define NB 64
#define NQ 900
#define NCLS 81     // C+1
#define NLAB 81     // possible argmax labels 0..80
#define NVERB 117
#define NBQ (NB*NQ)
#define NWORD 15    // max chunks per group (ceil(900/64))

// ---- wave64 max-reduce on the VALU pipe (DPP), result uniform in all lanes.
__device__ __forceinline__ float wave_max_dpp(float m) {
    unsigned mu;
    mu = __float_as_uint(m);
    m = fmaxf(m, __uint_as_float(__builtin_amdgcn_update_dpp(mu, mu, 0x111, 0xF, 0xF, false)));
    mu = __float_as_uint(m);
    m = fmaxf(m, __uint_as_float(__builtin_amdgcn_update_dpp(mu, mu, 0x112, 0xF, 0xF, false)));
    mu = __float_as_uint(m);
    m = fmaxf(m, __uint_as_float(__builtin_amdgcn_update_dpp(mu, mu, 0x114, 0xF, 0xF, false)));
    mu = __float_as_uint(m);
    m = fmaxf(m, __uint_as_float(__builtin_amdgcn_update_dpp(mu, mu, 0x118, 0xF, 0xF, false)));
    mu = __float_as_uint(m);
    m = fmaxf(m, __uint_as_float(__builtin_amdgcn_update_dpp(mu, mu, 0x142, 0xF, 0xF, false)));
    mu = __float_as_uint(m);
    m = fmaxf(m, __uint_as_float(__builtin_amdgcn_update_dpp(mu, mu, 0x143, 0xF, 0xF, false)));
    return __uint_as_float(__builtin_amdgcn_readlane(__float_as_uint(m), 63));
}

// ---- Kernel 0: correct_mat (exactly {0,1}) -> per-class 128-bit verb mask --
__global__ __launch_bounds__(256) void k0(
    const float* __restrict__ cmat, unsigned* __restrict__ bmask)
{
    int idx = blockIdx.x * 256 + threadIdx.x;
    if (idx >= NCLS * 4) return;
    int c = idx >> 2, w = idx & 3;
    unsigned m = 0;
    for (int k = 0; k < 32; ++k) {
        int v = w * 32 + k;
        if (v < NVERB) {
            bool bit = (c < NCLS - 1) ? (cmat[v * (NCLS - 1) + c] > 0.5f) : true;
            if (bit) m |= (1u << k);
        }
    }
    bmask[idx] = m;
}

// ---- Kernel A2: thread-per-row box scale + areas (pure streaming) ---------
__global__ __launch_bounds__(256) void kA2(
    const float* __restrict__ sub_boxes, const float* __restrict__ obj_boxes,
    const int* __restrict__ target_sizes,
    float* __restrict__ out_sb, float* __restrict__ out_ob,
    float* __restrict__ sar, float* __restrict__ oar)
{
    int idx = blockIdx.x * 256 + threadIdx.x;
    if (idx >= NBQ) return;
    int b = idx / NQ;
    float ih = (float)target_sizes[b * 2 + 0];
    float iw = (float)target_sizes[b * 2 + 1];

    float4 s = ((const float4*)sub_boxes)[idx];
    float x1 = (s.x - 0.5f * s.z) * iw, y1 = (s.y - 0.5f * s.w) * ih;
    float x2 = (s.x + 0.5f * s.z) * iw, y2 = (s.y + 0.5f * s.w) * ih;
    ((float4*)out_sb)[idx] = make_float4(x1, y1, x2, y2);
    sar[idx] = (x2 - x1 + 1.0f) * (y2 - y1 + 1.0f);

    float4 o = ((const float4*)obj_boxes)[idx];
    x1 = (o.x - 0.5f * o.z) * iw; y1 = (o.y - 0.5f * o.w) * ih;
    x2 = (o.x + 0.5f * o.z) * iw; y2 = (o.y + 0.5f * o.w) * ih;
    ((float4*)out_ob)[idx] = make_float4(x1, y1, x2, y2);
    oar[idx] = (x2 - x1 + 1.0f) * (y2 - y1 + 1.0f);
}

// -------- Kernel A: logits only — 4 rows/wave, bitmask masks ---------------
__global__ __launch_bounds__(256) void kA(
    const float* __restrict__ obj_logits, const float* __restrict__ verb_logits,
    const uint4* __restrict__ bmask,
    float* __restrict__ out_hoi, float* __restrict__ out_lab,
    float* __restrict__ ws_max, int* __restrict__ ws_lab)
{
    int wp   = (blockIdx.x * blockDim.x + threadIdx.x) >> 6;
    int lane = threadIdx.x & 63;
    int w0 = wp * 4;                 // 4 rows; 900 % 4 == 0 -> never cross batch

    // ---- issue ALL global loads first (16 independent) ----
    const float* ol = obj_logits  + (size_t)w0 * NCLS;
    const float* vl = verb_logits + (size_t)w0 * NVERB;
    float A[4], Bv[4], va[4], vb[4];
    #pragma unroll
    for (int r = 0; r < 4; ++r) {
        A[r]  = ol[r * NCLS + lane];
        Bv[r] = (lane < NCLS - 64) ? ol[r * NCLS + 64 + lane] : -3.4e38f;
        va[r] = vl[r * NVERB + lane];
        vb[r] = (lane < NVERB - 64) ? vl[r * NVERB + 64 + lane] : 0.0f;
    }

    // ---- argmax: DPP max + ballot index recovery ----
    float OS[4]; int MI[4];
    #pragma unroll
    for (int r = 0; r < 4; ++r) {
        float m = wave_max_dpp(fmaxf(A[r], Bv[r]));
        u64 balA = __ballot((int)(A[r] == m));
        u64 balB = __ballot((int)(lane < NCLS - 64 && Bv[r] == m));
        MI[r] = balA ? (__ffsll(balA) - 1) : (63 + __ffsll(balB));
        OS[r] = 1.0f / (1.0f + __expf(-m));
    }

    // ---- hoi scores: sigmoid * obj_score * bit-mask, row max ----
    float MX[4];
    #pragma unroll
    for (int r = 0; r < 4; ++r) {
        uint4 bm = bmask[MI[r]];
        unsigned wa = (lane < 32) ? bm.x : bm.y;
        unsigned wb = (lane < 32) ? bm.z : bm.w;
        float ka = ((wa >> (lane & 31)) & 1u) ? 1.0f : 0.0f;
        float kb = ((wb >> (lane & 31)) & 1u) ? 1.0f : 0.0f;
        float* oh = out_hoi + (size_t)(w0 + r) * NVERB;
        float ha = OS[r] * ka / (1.0f + __expf(-va[r]));
        float hb = -1.0f;
        if (lane < NVERB - 64) {
            hb = OS[r] * kb / (1.0f + __expf(-vb[r]));
            oh[64 + lane] = hb;
        }
        oh[lane] = ha;
        MX[r] = wave_max_dpp(fmaxf(ha, hb));
    }

    // ---- scalar per-row outputs (values are wave-uniform) ----
    if (lane < 4) {
        int   mi = (lane == 0) ? MI[0] : (lane == 1) ? MI[1] : (lane == 2) ? MI[2] : MI[3];
        float mx = (lane == 0) ? MX[0] : (lane == 1) ? MX[1] : (lane == 2) ? MX[2] : MX[3];
        out_lab[w0 + lane] = (float)mi;
        ws_lab[w0 + lane]  = mi;
        ws_max[w0 + lane]  = mx;
    }
}

// ---- Kernel B: wave-per-q rank-by-count; emits ws_ord + sorted labels -----
__global__ __launch_bounds__(256) void kB(
    const float* __restrict__ ws_max, const int* __restrict__ ws_lab,
    int* __restrict__ ws_ord, int* __restrict__ slab)
{
    __shared__ float sc[NQ];
    int b = blockIdx.y, t = threadIdx.x;
    for (int i = t; i < NQ; i += 256) sc[i] = ws_max[b * NQ + i];
    __syncthreads();
    int lane = t & 63, wv = t >> 6;
    int q = blockIdx.x * 4 + wv;             // grid.x = 225, 225*4 = 900
    float sq = sc[q];
    int rank = 0;
    #pragma unroll
    for (int c = 0; c < NWORD; ++c) {
        int j = c * 64 + lane;
        float sj = sc[min(j, NQ - 1)];
        bool p = (j < NQ) && ((sj > sq) || (sj == sq && j < q));
        rank += __popcll(__ballot((int)p));
    }
    if (lane == 0) {
        int dst = b * NQ + rank;
        ws_ord[dst] = q;
        slab[dst]   = ws_lab[b * NQ + q];
    }
}

// ------- Kernel E: per-(batch,label) greedy NMS, LDS-staged label scan -----
__device__ __forceinline__ float bc(float x, int r) {
    return __uint_as_float(__builtin_amdgcn_readlane(__float_as_uint(x), r));
}

__device__ __forceinline__ bool iou_pred(
    const float4& sj, const float4& oj, float saj, float oaj,
    float six, float siy, float siz, float siw,
    float oix, float oiy, float oiz, float oiw, float sai, float oai)
{
    float xx1 = fmaxf(six, sj.x), yy1 = fmaxf(siy, sj.y);
    float xx2 = fminf(siz, sj.z), yy2 = fminf(siw, sj.w);
    float w = fmaxf(0.0f, xx2 - xx1 + 1.0f);
    float h = fmaxf(0.0f, yy2 - yy1 + 1.0f);
    float iS = w * h, uS = sai + saj - iS;
    xx1 = fmaxf(oix, oj.x); yy1 = fmaxf(oiy, oj.y);
    xx2 = fminf(oiz, oj.z); yy2 = fminf(oiw, oj.w);
    w = fmaxf(0.0f, xx2 - xx1 + 1.0f);
    h = fmaxf(0.0f, yy2 - yy1 + 1.0f);
    float iO = w * h, uO = oai + oaj - iO;
    // iouS * sqrt(iouO) > 0.7  <=>  iS^2*iO > 0.49*uS^2*uO  (all nonneg)
    return iS * iS * iO > 0.49f * uS * uS * uO;
}

#define LPB 21   // labels per block (4 blocks x 21 >= 81)
__global__ __launch_bounds__(256) void kE(
    const float* __restrict__ out_sb, const float* __restrict__ out_ob,
    const float* __restrict__ sar, const float* __restrict__ oar,
    const int* __restrict__ slab, const int* __restrict__ ws_ord,
    float* __restrict__ out_keep)
{
    __shared__ unsigned short Ls[NQ];       // sorted labels (staged once)
    __shared__ unsigned short Lo[NQ];       // sorted -> original q (staged once)
    __shared__ unsigned short mem[4][NQ];   // per-wave member ORIGINAL indices
    __shared__ u64 keptm[4][NWORD];         // per-wave kept bits per chunk
    const float4* sb4 = (const float4*)out_sb;
    const float4* ob4 = (const float4*)out_ob;
    int b = blockIdx.y, base = b * NQ;
    int t = threadIdx.x, lane = t & 63, wv = t >> 6;

    for (int k = t; k < NQ; k += 256) {
        Ls[k] = (unsigned short)slab[base + k];
        Lo[k] = (unsigned short)ws_ord[base + k];
    }
    __syncthreads();

    int lend = min(blockIdx.x * LPB + LPB, NLAB);
    for (int l = blockIdx.x * LPB + wv; l < lend; l += 4) {
        // ---- collect members of label l in rank order (LDS ballot scan) ----
        int g = 0;
        #pragma unroll
        for (int k0_ = 0; k0_ < NQ; k0_ += 64) {
            int k = k0_ + lane;
            bool isl = (k < NQ) && ((int)Ls[k] == l);
            u64 bal = __ballot((int)isl);
            if (isl) {
                int pos = g + __popcll(bal & (((u64)1 << lane) - 1));
                mem[wv][pos] = Lo[k];
            }
            g += __popcll(bal);
        }

        int nch = (g + 63) >> 6;
        for (int c = 0; c < nch; ++c) {
            int rows = min(64, g - c * 64);
            bool vld = lane < rows;
            int oq = vld ? (int)mem[wv][c * 64 + lane] : 0;
            float4 sj = sb4[base + oq];
            float4 oj = ob4[base + oq];
            float saj = sar[base + oq], oaj = oar[base + oq];

            // ---- cross-chunk: suppression by kept members of earlier chunks ----
            u64 pre = 0ull;
            for (int e = 0; e < c; ++e) {
                int oqE = (int)mem[wv][e * 64 + lane];   // chunk e is always full
                float4 sE = sb4[base + oqE];
                float4 oE = ob4[base + oqE];
                float saE = sar[base + oqE], oaE = oar[base + oqE];
                u64 ke = keptm[wv][e];
                for (int r = 0; r < 64; ++r) {
                    if ((ke >> r) & 1ull) {
                        bool p = vld && iou_pred(sj, oj, saj, oaj,
                            bc(sE.x, r), bc(sE.y, r), bc(sE.z, r), bc(sE.w, r),
                            bc(oE.x, r), bc(oE.y, r), bc(oE.z, r), bc(oE.w, r),
                            bc(saE, r), bc(oaE, r));
                        pre |= __ballot((int)p);
                    }
                }
            }

            // ---- within-chunk cand words: lane r keeps row r's column word ----
            u64 myword = 0ull;
            for (int r = 0; r < rows; ++r) {
                bool p = vld && (lane > r) && iou_pred(sj, oj, saj, oaj,
                    bc(sj.x, r), bc(sj.y, r), bc(sj.z, r), bc(sj.w, r),
                    bc(oj.x, r), bc(oj.y, r), bc(oj.z, r), bc(oj.w, r),
                    bc(saj, r), bc(oaj, r));
                u64 bal = __ballot((int)p);
                if (lane == r) myword = bal;
            }

            // ---- sequential resolution (SALU chain over uniform values) ----
            unsigned ilo = (unsigned)myword, ihi = (unsigned)(myword >> 32);
            u64 supp = pre;
            for (int r = 0; r < rows; ++r) {
                u64 rowr = ((u64)__builtin_amdgcn_readlane(ihi, r) << 32)
                         |  (u64)__builtin_amdgcn_readlane(ilo, r);
                supp |= ((supp >> r) & 1ull) ? 0ull : rowr;
            }
            u64 keep = ~supp;
            if (lane == 0)
                keptm[wv][c] = keep & ((rows == 64) ? ~0ull : (((u64)1 << rows) - 1));
            if (vld)
                out_keep[base + oq] = ((keep >> lane) & 1ull) ? 1.0f : 0.0f;
        }
    }
}

extern "C" void kernel_launch(void* const* d_in, const int* in_sizes, int n_in,
                              void* d_out, int out_size, void* d_ws, size_t ws_size,
                              hipStream_t stream)
{
    const float* obj_logits   = (const float*)d_in[0];
    const float* verb_logits  = (const float*)d_in[1];
    const float* sub_boxes    = (const float*)d_in[2];
    const float* obj_boxes    = (const float*)d_in[3];
    const int*   target_sizes = (const int*)d_in[4];
    const float* cmat         = (const float*)d_in[5];

    float* out      = (float*)d_out;
    float* out_hoi  = out;
    float* out_lab  = out_hoi + (size_t)NBQ * NVERB;
    float* out_sb   = out_lab + NBQ;
    float* out_ob   = out_sb + (size_t)NBQ * 4;
    float* out_keep = out_ob + (size_t)NBQ * 4;

    // workspace layout
    char* w = (char*)d_ws;
    float*    ws_max = (float*)w;        w += (size_t)NBQ * 4;
    float*    sar    = (float*)w;        w += (size_t)NBQ * 4;
    float*    oar    = (float*)w;        w += (size_t)NBQ * 4;
    int*      ws_lab = (int*)w;          w += (size_t)NBQ * 4;
    int*      slab   = (int*)w;          w += (size_t)NBQ * 4;
    int*      ws_ord = (int*)w;          w += (size_t)NBQ * 4;
    unsigned* bmask  = (unsigned*)w;     w += (size_t)NCLS * 4 * 4;

    k0<<<(NCLS * 4 + 255) / 256, 256, 0, stream>>>(cmat, bmask);
    kA2<<<(NBQ + 255) / 256, 256, 0, stream>>>(sub_boxes, obj_boxes, target_sizes,
                                               out_sb, out_ob, sar, oar);
    kA<<<NBQ / 16, 256, 0, stream>>>(obj_logits, verb_logits, (const uint4*)bmask,
                                     out_hoi, out_lab, ws_max, ws_lab);
    kB<<<dim3(NQ / 4, NB), 256, 0, stream>>>(ws_max, ws_lab, ws_ord, slab);
    kE<<<dim3((NLAB + LPB - 1) / LPB, NB), 256, 0, stream>>>(out_sb, out_ob, sar, oar,
                                                             slab, ws_ord, out_keep);
}

// Round 11
// 81.969 us; speedup vs baseline: 1.1196x; 1.1196x over previous
//
#include <hip/hip_runtime.h>

typedef unsigned long long u64;

#define NB 64
#define NQ 900
#define NCLS 81     // C+1
#define NLAB 81     // possible argmax labels 0..80
#define NVERB 117
#define NBQ (NB*NQ)
#define NWORD 15    // max chunks per group (ceil(900/64))
#define RPW 8       // rows per wave in kA

// ---- wave64 max-reduce on the VALU pipe (DPP), result uniform in all lanes.
__device__ __forceinline__ float wave_max_dpp(float m) {
    unsigned mu;
    mu = __float_as_uint(m);
    m = fmaxf(m, __uint_as_float(__builtin_amdgcn_update_dpp(mu, mu, 0x111, 0xF, 0xF, false)));
    mu = __float_as_uint(m);
    m = fmaxf(m, __uint_as_float(__builtin_amdgcn_update_dpp(mu, mu, 0x112, 0xF, 0xF, false)));
    mu = __float_as_uint(m);
    m = fmaxf(m, __uint_as_float(__builtin_amdgcn_update_dpp(mu, mu, 0x114, 0xF, 0xF, false)));
    mu = __float_as_uint(m);
    m = fmaxf(m, __uint_as_float(__builtin_amdgcn_update_dpp(mu, mu, 0x118, 0xF, 0xF, false)));
    mu = __float_as_uint(m);
    m = fmaxf(m, __uint_as_float(__builtin_amdgcn_update_dpp(mu, mu, 0x142, 0xF, 0xF, false)));
    mu = __float_as_uint(m);
    m = fmaxf(m, __uint_as_float(__builtin_amdgcn_update_dpp(mu, mu, 0x143, 0xF, 0xF, false)));
    return __uint_as_float(__builtin_amdgcn_readlane(__float_as_uint(m), 63));
}

// ---- Kernel 0: correct_mat (exactly {0,1}) -> per-class 128-bit verb mask --
__global__ __launch_bounds__(256) void k0(
    const float* __restrict__ cmat, unsigned* __restrict__ bmask)
{
    int idx = blockIdx.x * 256 + threadIdx.x;
    if (idx >= NCLS * 4) return;
    int c = idx >> 2, w = idx & 3;
    unsigned m = 0;
    for (int k = 0; k < 32; ++k) {
        int v = w * 32 + k;
        if (v < NVERB) {
            bool bit = (c < NCLS - 1) ? (cmat[v * (NCLS - 1) + c] > 0.5f) : true;
            if (bit) m |= (1u << k);
        }
    }
    bmask[idx] = m;
}

// ---- Kernel A: 8 rows/wave, all loads front-loaded, fused box scaling -----
__global__ __launch_bounds__(256) void kA(
    const float* __restrict__ obj_logits, const float* __restrict__ verb_logits,
    const float* __restrict__ sub_boxes, const float* __restrict__ obj_boxes,
    const int* __restrict__ target_sizes, const uint4* __restrict__ bmask,
    float* __restrict__ out_hoi, float* __restrict__ out_lab,
    float* __restrict__ out_sb, float* __restrict__ out_ob,
    float* __restrict__ ws_max, int* __restrict__ ws_lab,
    float* __restrict__ sar, float* __restrict__ oar)
{
    int wp   = (blockIdx.x * blockDim.x + threadIdx.x) >> 6;
    int lane = threadIdx.x & 63;
    int w0 = wp * RPW;

    // ---- issue ALL 32 global loads first (independent streams) ----
    const float* ol = obj_logits  + (size_t)w0 * NCLS;
    const float* vl = verb_logits + (size_t)w0 * NVERB;
    float A[RPW], Bv[RPW], va[RPW], vb[RPW];
    #pragma unroll
    for (int r = 0; r < RPW; ++r) {
        A[r]  = ol[r * NCLS + lane];
        Bv[r] = (lane < NCLS - 64) ? ol[r * NCLS + 64 + lane] : -3.4e38f;
        va[r] = vl[r * NVERB + lane];
        vb[r] = (lane < NVERB - 64) ? vl[r * NVERB + 64 + lane] : 0.0f;
    }

    // ---- argmax: DPP max + ballot index recovery ----
    float OS[RPW]; int MI[RPW];
    #pragma unroll
    for (int r = 0; r < RPW; ++r) {
        float m = wave_max_dpp(fmaxf(A[r], Bv[r]));
        u64 balA = __ballot((int)(A[r] == m));
        u64 balB = __ballot((int)(lane < NCLS - 64 && Bv[r] == m));
        MI[r] = balA ? (__ffsll(balA) - 1) : (63 + __ffsll(balB));
        OS[r] = 1.0f / (1.0f + __expf(-m));
    }

    // ---- hoi scores: sigmoid * obj_score * bit-mask, row max ----
    float MX[RPW];
    #pragma unroll
    for (int r = 0; r < RPW; ++r) {
        uint4 bm = bmask[MI[r]];
        unsigned wa = (lane < 32) ? bm.x : bm.y;
        unsigned wb = (lane < 32) ? bm.z : bm.w;
        float ka = ((wa >> (lane & 31)) & 1u) ? 1.0f : 0.0f;
        float kb = ((wb >> (lane & 31)) & 1u) ? 1.0f : 0.0f;
        float* oh = out_hoi + (size_t)(w0 + r) * NVERB;
        float ha = OS[r] * ka / (1.0f + __expf(-va[r]));
        float hb = -1.0f;
        if (lane < NVERB - 64) {
            hb = OS[r] * kb / (1.0f + __expf(-vb[r]));
            oh[64 + lane] = hb;
        }
        oh[lane] = ha;
        MX[r] = wave_max_dpp(fmaxf(ha, hb));
    }

    // ---- per-row scalar outputs ----
    if (lane < RPW) {
        int mi; float mx;
        #pragma unroll
        for (int r = 0; r < RPW; ++r) if (lane == r) { mi = MI[r]; mx = MX[r]; }
        out_lab[w0 + lane] = (float)mi;
        ws_lab[w0 + lane]  = mi;
        ws_max[w0 + lane]  = mx;
    }

    // ---- fused box scale + area: lanes 0-15 = {8 rows} x {sub,obj} ----
    if (lane < 2 * RPW) {
        int row = w0 + (lane >> 1);
        int b = row / NQ;                    // per-row batch (w0 may straddle)
        const float* bx = ((lane & 1) == 0 ? sub_boxes : obj_boxes) + (size_t)row * 4;
        float* o = ((lane & 1) == 0 ? out_sb : out_ob) + (size_t)row * 4;
        float ih = (float)target_sizes[b * 2 + 0];
        float iw = (float)target_sizes[b * 2 + 1];
        float4 v = *(const float4*)bx;
        float x1 = (v.x - 0.5f * v.z) * iw, y1 = (v.y - 0.5f * v.w) * ih;
        float x2 = (v.x + 0.5f * v.z) * iw, y2 = (v.y + 0.5f * v.w) * ih;
        *(float4*)o = make_float4(x1, y1, x2, y2);
        float ar = (x2 - x1 + 1.0f) * (y2 - y1 + 1.0f);
        ((lane & 1) == 0 ? sar : oar)[row] = ar;
    }
}

// ---- Kernel B: wave-per-q rank-by-count; emits ws_ord + sorted labels -----
__global__ __launch_bounds__(256) void kB(
    const float* __restrict__ ws_max, const int* __restrict__ ws_lab,
    int* __restrict__ ws_ord, int* __restrict__ slab)
{
    __shared__ float sc[NQ];
    int b = blockIdx.y, t = threadIdx.x;
    for (int i = t; i < NQ; i += 256) sc[i] = ws_max[b * NQ + i];
    __syncthreads();
    int lane = t & 63, wv = t >> 6;
    int q = blockIdx.x * 4 + wv;             // grid.x = 225, 225*4 = 900
    float sq = sc[q];
    int rank = 0;
    #pragma unroll
    for (int c = 0; c < NWORD; ++c) {
        int j = c * 64 + lane;
        float sj = sc[min(j, NQ - 1)];
        bool p = (j < NQ) && ((sj > sq) || (sj == sq && j < q));
        rank += __popcll(__ballot((int)p));
    }
    if (lane == 0) {
        int dst = b * NQ + rank;
        ws_ord[dst] = q;
        slab[dst]   = ws_lab[b * NQ + q];
    }
}

// ---------------- Kernel E: per-(batch,label) greedy NMS, one wave each ----
// (R9 version — measured ~4 us; one label per wave, 84 parallel waves/batch)
__device__ __forceinline__ float bc(float x, int r) {
    return __uint_as_float(__builtin_amdgcn_readlane(__float_as_uint(x), r));
}

__device__ __forceinline__ bool iou_pred(
    const float4& sj, const float4& oj, float saj, float oaj,
    float six, float siy, float siz, float siw,
    float oix, float oiy, float oiz, float oiw, float sai, float oai)
{
    float xx1 = fmaxf(six, sj.x), yy1 = fmaxf(siy, sj.y);
    float xx2 = fminf(siz, sj.z), yy2 = fminf(siw, sj.w);
    float w = fmaxf(0.0f, xx2 - xx1 + 1.0f);
    float h = fmaxf(0.0f, yy2 - yy1 + 1.0f);
    float iS = w * h, uS = sai + saj - iS;
    xx1 = fmaxf(oix, oj.x); yy1 = fmaxf(oiy, oj.y);
    xx2 = fminf(oiz, oj.z); yy2 = fminf(oiw, oj.w);
    w = fmaxf(0.0f, xx2 - xx1 + 1.0f);
    h = fmaxf(0.0f, yy2 - yy1 + 1.0f);
    float iO = w * h, uO = oai + oaj - iO;
    // iouS * sqrt(iouO) > 0.7  <=>  iS^2*iO > 0.49*uS^2*uO  (all nonneg)
    return iS * iS * iO > 0.49f * uS * uS * uO;
}

__global__ __launch_bounds__(256) void kE(
    const float* __restrict__ out_sb, const float* __restrict__ out_ob,
    const float* __restrict__ sar, const float* __restrict__ oar,
    const int* __restrict__ slab, const int* __restrict__ ws_ord,
    float* __restrict__ out_keep)
{
    __shared__ unsigned short mem[4][NQ];   // per-wave member ORIGINAL indices
    __shared__ u64 keptm[4][NWORD];         // per-wave kept bits per chunk
    const float4* sb4 = (const float4*)out_sb;
    const float4* ob4 = (const float4*)out_ob;
    int b = blockIdx.y, base = b * NQ;
    int lane = threadIdx.x & 63, wv = threadIdx.x >> 6;
    int l = blockIdx.x * 4 + wv;
    if (l >= NLAB) return;

    // ---- collect members of label l in rank order (ballot-compaction) ----
    int g = 0;
    for (int k0_ = 0; k0_ < NQ; k0_ += 64) {
        int k = k0_ + lane;
        int lb = (k < NQ) ? slab[base + k] : -1;
        int oq = (k < NQ) ? ws_ord[base + k] : 0;
        u64 bal = __ballot((int)(lb == l));
        if (lb == l) {
            int pos = g + __popcll(bal & (((u64)1 << lane) - 1));
            mem[wv][pos] = (unsigned short)oq;
        }
        g += __popcll(bal);
    }

    int nch = (g + 63) >> 6;
    for (int c = 0; c < nch; ++c) {
        int rows = min(64, g - c * 64);
        bool vld = lane < rows;
        int oq = vld ? (int)mem[wv][c * 64 + lane] : 0;
        float4 sj = sb4[base + oq];
        float4 oj = ob4[base + oq];
        float saj = sar[base + oq], oaj = oar[base + oq];

        // ---- cross-chunk: suppression by kept members of earlier chunks ----
        u64 pre = 0ull;
        for (int e = 0; e < c; ++e) {
            int oqE = (int)mem[wv][e * 64 + lane];   // chunk e is always full
            float4 sE = sb4[base + oqE];
            float4 oE = ob4[base + oqE];
            float saE = sar[base + oqE], oaE = oar[base + oqE];
            u64 ke = keptm[wv][e];
            for (int r = 0; r < 64; ++r) {
                if ((ke >> r) & 1ull) {
                    bool p = vld && iou_pred(sj, oj, saj, oaj,
                        bc(sE.x, r), bc(sE.y, r), bc(sE.z, r), bc(sE.w, r),
                        bc(oE.x, r), bc(oE.y, r), bc(oE.z, r), bc(oE.w, r),
                        bc(saE, r), bc(oaE, r));
                    pre |= __ballot((int)p);
                }
            }
        }

        // ---- within-chunk cand words: lane r keeps row r's column word ----
        u64 myword = 0ull;
        for (int r = 0; r < rows; ++r) {
            bool p = vld && (lane > r) && iou_pred(sj, oj, saj, oaj,
                bc(sj.x, r), bc(sj.y, r), bc(sj.z, r), bc(sj.w, r),
                bc(oj.x, r), bc(oj.y, r), bc(oj.z, r), bc(oj.w, r),
                bc(saj, r), bc(oaj, r));
            u64 bal = __ballot((int)p);
            if (lane == r) myword = bal;
        }

        // ---- sequential resolution (SALU chain over uniform values) ----
        unsigned ilo = (unsigned)myword, ihi = (unsigned)(myword >> 32);
        u64 supp = pre;
        for (int r = 0; r < rows; ++r) {
            u64 rowr = ((u64)__builtin_amdgcn_readlane(ihi, r) << 32)
                     |  (u64)__builtin_amdgcn_readlane(ilo, r);
            supp |= ((supp >> r) & 1ull) ? 0ull : rowr;
        }
        u64 keep = ~supp;
        if (lane == 0)
            keptm[wv][c] = keep & ((rows == 64) ? ~0ull : (((u64)1 << rows) - 1));
        if (vld)
            out_keep[base + oq] = ((keep >> lane) & 1ull) ? 1.0f : 0.0f;
    }
}

extern "C" void kernel_launch(void* const* d_in, const int* in_sizes, int n_in,
                              void* d_out, int out_size, void* d_ws, size_t ws_size,
                              hipStream_t stream)
{
    const float* obj_logits   = (const float*)d_in[0];
    const float* verb_logits  = (const float*)d_in[1];
    const float* sub_boxes    = (const float*)d_in[2];
    const float* obj_boxes    = (const float*)d_in[3];
    const int*   target_sizes = (const int*)d_in[4];
    const float* cmat         = (const float*)d_in[5];

    float* out      = (float*)d_out;
    float* out_hoi  = out;
    float* out_lab  = out_hoi + (size_t)NBQ * NVERB;
    float* out_sb   = out_lab + NBQ;
    float* out_ob   = out_sb + (size_t)NBQ * 4;
    float* out_keep = out_ob + (size_t)NBQ * 4;

    // workspace layout
    char* w = (char*)d_ws;
    float*    ws_max = (float*)w;        w += (size_t)NBQ * 4;
    float*    sar    = (float*)w;        w += (size_t)NBQ * 4;
    float*    oar    = (float*)w;        w += (size_t)NBQ * 4;
    int*      ws_lab = (int*)w;          w += (size_t)NBQ * 4;
    int*      slab   = (int*)w;          w += (size_t)NBQ * 4;
    int*      ws_ord = (int*)w;          w += (size_t)NBQ * 4;
    unsigned* bmask  = (unsigned*)w;     w += (size_t)NCLS * 4 * 4;

    k0<<<(NCLS * 4 + 255) / 256, 256, 0, stream>>>(cmat, bmask);
    kA<<<NBQ / (RPW * 4), 256, 0, stream>>>(obj_logits, verb_logits,
                                            sub_boxes, obj_boxes, target_sizes,
                                            (const uint4*)bmask,
                                            out_hoi, out_lab, out_sb, out_ob,
                                            ws_max, ws_lab, sar, oar);
    kB<<<dim3(NQ / 4, NB), 256, 0, stream>>>(ws_max, ws_lab, ws_ord, slab);
    kE<<<dim3((NLAB + 3) / 4, NB), 256, 0, stream>>>(out_sb, out_ob, sar, oar,
                                                     slab, ws_ord, out_keep);
}

// Round 12
// 76.880 us; speedup vs baseline: 1.1937x; 1.0662x over previous
//
#include <hip/hip_runtime.h>

typedef unsigned long long u64;

#define NB 64
#define NQ 900
#define NCLS 81     // C+1
#define NLAB 81     // possible argmax labels 0..80
#define NVERB 117
#define NBQ (NB*NQ)
#define NWORD 15    // max chunks per group (ceil(900/64))

// ---- wave64 max-reduce on the VALU pipe (DPP), result uniform in all lanes.
__device__ __forceinline__ float wave_max_dpp(float m) {
    unsigned mu;
    mu = __float_as_uint(m);
    m = fmaxf(m, __uint_as_float(__builtin_amdgcn_update_dpp(mu, mu, 0x111, 0xF, 0xF, false)));
    mu = __float_as_uint(m);
    m = fmaxf(m, __uint_as_float(__builtin_amdgcn_update_dpp(mu, mu, 0x112, 0xF, 0xF, false)));
    mu = __float_as_uint(m);
    m = fmaxf(m, __uint_as_float(__builtin_amdgcn_update_dpp(mu, mu, 0x114, 0xF, 0xF, false)));
    mu = __float_as_uint(m);
    m = fmaxf(m, __uint_as_float(__builtin_amdgcn_update_dpp(mu, mu, 0x118, 0xF, 0xF, false)));
    mu = __float_as_uint(m);
    m = fmaxf(m, __uint_as_float(__builtin_amdgcn_update_dpp(mu, mu, 0x142, 0xF, 0xF, false)));
    mu = __float_as_uint(m);
    m = fmaxf(m, __uint_as_float(__builtin_amdgcn_update_dpp(mu, mu, 0x143, 0xF, 0xF, false)));
    return __uint_as_float(__builtin_amdgcn_readlane(__float_as_uint(m), 63));
}

// ---- Kernel 0: correct_mat (exactly {0,1}) -> per-class 128-bit verb mask --
__global__ __launch_bounds__(256) void k0(
    const float* __restrict__ cmat, unsigned* __restrict__ bmask)
{
    int idx = blockIdx.x * 256 + threadIdx.x;
    if (idx >= NCLS * 4) return;
    int c = idx >> 2, w = idx & 3;
    unsigned m = 0;
    for (int k = 0; k < 32; ++k) {
        int v = w * 32 + k;
        if (v < NVERB) {
            bool bit = (c < NCLS - 1) ? (cmat[v * (NCLS - 1) + c] > 0.5f) : true;
            if (bit) m |= (1u << k);
        }
    }
    bmask[idx] = m;
}

// ---- Kernel A: 4 rows/wave (best measured), fast div, nontemporal stores --
__global__ __launch_bounds__(256) void kA(
    const float* __restrict__ obj_logits, const float* __restrict__ verb_logits,
    const float* __restrict__ sub_boxes, const float* __restrict__ obj_boxes,
    const int* __restrict__ target_sizes, const uint4* __restrict__ bmask,
    float* __restrict__ out_hoi, float* __restrict__ out_lab,
    float* __restrict__ out_sb, float* __restrict__ out_ob,
    float* __restrict__ ws_max, int* __restrict__ ws_lab,
    float* __restrict__ sar, float* __restrict__ oar)
{
    int wp   = (blockIdx.x * blockDim.x + threadIdx.x) >> 6;
    int lane = threadIdx.x & 63;
    int w0 = wp * 4;                 // 4 rows; 900 % 4 == 0 -> never cross batch
    int b = w0 / NQ;

    // ---- issue ALL 16 global loads first (independent streams) ----
    const float* ol = obj_logits  + (size_t)w0 * NCLS;
    const float* vl = verb_logits + (size_t)w0 * NVERB;
    float A[4], Bv[4], va[4], vb[4];
    #pragma unroll
    for (int r = 0; r < 4; ++r) {
        A[r]  = ol[r * NCLS + lane];
        Bv[r] = (lane < NCLS - 64) ? ol[r * NCLS + 64 + lane] : -3.4e38f;
        va[r] = vl[r * NVERB + lane];
        vb[r] = (lane < NVERB - 64) ? vl[r * NVERB + 64 + lane] : 0.0f;
    }

    // ---- argmax: DPP max + ballot index recovery ----
    float OS[4]; int MI[4];
    #pragma unroll
    for (int r = 0; r < 4; ++r) {
        float m = wave_max_dpp(fmaxf(A[r], Bv[r]));
        u64 balA = __ballot((int)(A[r] == m));
        u64 balB = __ballot((int)(lane < NCLS - 64 && Bv[r] == m));
        MI[r] = balA ? (__ffsll(balA) - 1) : (63 + __ffsll(balB));
        OS[r] = __fdividef(1.0f, 1.0f + __expf(-m));
    }

    // ---- hoi scores: sigmoid * obj_score * bit-mask, row max ----
    float MX[4];
    #pragma unroll
    for (int r = 0; r < 4; ++r) {
        uint4 bm = bmask[MI[r]];
        unsigned wa = (lane < 32) ? bm.x : bm.y;
        unsigned wb = (lane < 32) ? bm.z : bm.w;
        float ka = ((wa >> (lane & 31)) & 1u) ? 1.0f : 0.0f;
        float kb = ((wb >> (lane & 31)) & 1u) ? 1.0f : 0.0f;
        float* oh = out_hoi + (size_t)(w0 + r) * NVERB;
        float ha = __fdividef(OS[r] * ka, 1.0f + __expf(-va[r]));
        float hb = -1.0f;
        if (lane < NVERB - 64) {
            hb = __fdividef(OS[r] * kb, 1.0f + __expf(-vb[r]));
            __builtin_nontemporal_store(hb, &oh[64 + lane]);
        }
        __builtin_nontemporal_store(ha, &oh[lane]);
        MX[r] = wave_max_dpp(fmaxf(ha, hb));
    }

    // ---- scalar per-row outputs (values are wave-uniform) ----
    if (lane < 4) {
        int   mi = (lane == 0) ? MI[0] : (lane == 1) ? MI[1] : (lane == 2) ? MI[2] : MI[3];
        float mx = (lane == 0) ? MX[0] : (lane == 1) ? MX[1] : (lane == 2) ? MX[2] : MX[3];
        out_lab[w0 + lane] = (float)mi;
        ws_lab[w0 + lane]  = mi;
        ws_max[w0 + lane]  = mx;
    }

    // ---- fused box scale + area: lanes 0-7 = {4 rows} x {sub,obj} ----
    if (lane < 8) {
        int row = w0 + (lane >> 1);
        const float* bx = ((lane & 1) == 0 ? sub_boxes : obj_boxes) + (size_t)row * 4;
        float* o = ((lane & 1) == 0 ? out_sb : out_ob) + (size_t)row * 4;
        float ih = (float)target_sizes[b * 2 + 0];
        float iw = (float)target_sizes[b * 2 + 1];
        float4 v = *(const float4*)bx;
        float x1 = (v.x - 0.5f * v.z) * iw, y1 = (v.y - 0.5f * v.w) * ih;
        float x2 = (v.x + 0.5f * v.z) * iw, y2 = (v.y + 0.5f * v.w) * ih;
        *(float4*)o = make_float4(x1, y1, x2, y2);
        float ar = (x2 - x1 + 1.0f) * (y2 - y1 + 1.0f);
        ((lane & 1) == 0 ? sar : oar)[row] = ar;
    }
}

// ---- Kernel B: wave-per-q rank-by-count; emits ws_ord + sorted labels -----
__global__ __launch_bounds__(256) void kB(
    const float* __restrict__ ws_max, const int* __restrict__ ws_lab,
    int* __restrict__ ws_ord, int* __restrict__ slab)
{
    __shared__ float sc[NQ];
    int b = blockIdx.y, t = threadIdx.x;
    for (int i = t; i < NQ; i += 256) sc[i] = ws_max[b * NQ + i];
    __syncthreads();
    int lane = t & 63, wv = t >> 6;
    int q = blockIdx.x * 4 + wv;             // grid.x = 225, 225*4 = 900
    float sq = sc[q];
    int rank = 0;
    #pragma unroll
    for (int c = 0; c < NWORD; ++c) {
        int j = c * 64 + lane;
        float sj = sc[min(j, NQ - 1)];
        bool p = (j < NQ) && ((sj > sq) || (sj == sq && j < q));
        rank += __popcll(__ballot((int)p));
    }
    if (lane == 0) {
        int dst = b * NQ + rank;
        ws_ord[dst] = q;
        slab[dst]   = ws_lab[b * NQ + q];
    }
}

// ---------------- Kernel E: per-(batch,label) greedy NMS, one wave each ----
__device__ __forceinline__ float bc(float x, int r) {
    return __uint_as_float(__builtin_amdgcn_readlane(__float_as_uint(x), r));
}

__device__ __forceinline__ bool iou_pred(
    const float4& sj, const float4& oj, float saj, float oaj,
    float six, float siy, float siz, float siw,
    float oix, float oiy, float oiz, float oiw, float sai, float oai)
{
    float xx1 = fmaxf(six, sj.x), yy1 = fmaxf(siy, sj.y);
    float xx2 = fminf(siz, sj.z), yy2 = fminf(siw, sj.w);
    float w = fmaxf(0.0f, xx2 - xx1 + 1.0f);
    float h = fmaxf(0.0f, yy2 - yy1 + 1.0f);
    float iS = w * h, uS = sai + saj - iS;
    xx1 = fmaxf(oix, oj.x); yy1 = fmaxf(oiy, oj.y);
    xx2 = fminf(oiz, oj.z); yy2 = fminf(oiw, oj.w);
    w = fmaxf(0.0f, xx2 - xx1 + 1.0f);
    h = fmaxf(0.0f, yy2 - yy1 + 1.0f);
    float iO = w * h, uO = oai + oaj - iO;
    // iouS * sqrt(iouO) > 0.7  <=>  iS^2*iO > 0.49*uS^2*uO  (all nonneg)
    return iS * iS * iO > 0.49f * uS * uS * uO;
}

__global__ __launch_bounds__(256) void kE(
    const float* __restrict__ out_sb, const float* __restrict__ out_ob,
    const float* __restrict__ sar, const float* __restrict__ oar,
    const int* __restrict__ slab, const int* __restrict__ ws_ord,
    float* __restrict__ out_keep)
{
    __shared__ unsigned short mem[4][NQ];   // per-wave member ORIGINAL indices
    __shared__ u64 keptm[4][NWORD];         // per-wave kept bits per chunk
    const float4* sb4 = (const float4*)out_sb;
    const float4* ob4 = (const float4*)out_ob;
    int b = blockIdx.y, base = b * NQ;
    int lane = threadIdx.x & 63, wv = threadIdx.x >> 6;
    int l = blockIdx.x * 4 + wv;
    if (l >= NLAB) return;

    // ---- collect members of label l in rank order (ballot-compaction) ----
    int g = 0;
    for (int k0_ = 0; k0_ < NQ; k0_ += 64) {
        int k = k0_ + lane;
        int lb = (k < NQ) ? slab[base + k] : -1;
        int oq = (k < NQ) ? ws_ord[base + k] : 0;
        u64 bal = __ballot((int)(lb == l));
        if (lb == l) {
            int pos = g + __popcll(bal & (((u64)1 << lane) - 1));
            mem[wv][pos] = (unsigned short)oq;
        }
        g += __popcll(bal);
    }

    int nch = (g + 63) >> 6;
    for (int c = 0; c < nch; ++c) {
        int rows = min(64, g - c * 64);
        bool vld = lane < rows;
        int oq = vld ? (int)mem[wv][c * 64 + lane] : 0;
        float4 sj = sb4[base + oq];
        float4 oj = ob4[base + oq];
        float saj = sar[base + oq], oaj = oar[base + oq];

        // ---- cross-chunk: suppression by kept members of earlier chunks ----
        u64 pre = 0ull;
        for (int e = 0; e < c; ++e) {
            int oqE = (int)mem[wv][e * 64 + lane];   // chunk e is always full
            float4 sE = sb4[base + oqE];
            float4 oE = ob4[base + oqE];
            float saE = sar[base + oqE], oaE = oar[base + oqE];
            u64 ke = keptm[wv][e];
            for (int r = 0; r < 64; ++r) {
                if ((ke >> r) & 1ull) {
                    bool p = vld && iou_pred(sj, oj, saj, oaj,
                        bc(sE.x, r), bc(sE.y, r), bc(sE.z, r), bc(sE.w, r),
                        bc(oE.x, r), bc(oE.y, r), bc(oE.z, r), bc(oE.w, r),
                        bc(saE, r), bc(oaE, r));
                    pre |= __ballot((int)p);
                }
            }
        }

        // ---- within-chunk cand words: lane r keeps row r's column word ----
        u64 myword = 0ull;
        for (int r = 0; r < rows; ++r) {
            bool p = vld && (lane > r) && iou_pred(sj, oj, saj, oaj,
                bc(sj.x, r), bc(sj.y, r), bc(sj.z, r), bc(sj.w, r),
                bc(oj.x, r), bc(oj.y, r), bc(oj.z, r), bc(oj.w, r),
                bc(saj, r), bc(oaj, r));
            u64 bal = __ballot((int)p);
            if (lane == r) myword = bal;
        }

        // ---- sequential resolution (SALU chain over uniform values) ----
        unsigned ilo = (unsigned)myword, ihi = (unsigned)(myword >> 32);
        u64 supp = pre;
        for (int r = 0; r < rows; ++r) {
            u64 rowr = ((u64)__builtin_amdgcn_readlane(ihi, r) << 32)
                     |  (u64)__builtin_amdgcn_readlane(ilo, r);
            supp |= ((supp >> r) & 1ull) ? 0ull : rowr;
        }
        u64 keep = ~supp;
        if (lane == 0)
            keptm[wv][c] = keep & ((rows == 64) ? ~0ull : (((u64)1 << rows) - 1));
        if (vld)
            out_keep[base + oq] = ((keep >> lane) & 1ull) ? 1.0f : 0.0f;
    }
}

extern "C" void kernel_launch(void* const* d_in, const int* in_sizes, int n_in,
                              void* d_out, int out_size, void* d_ws, size_t ws_size,
                              hipStream_t stream)
{
    const float* obj_logits   = (const float*)d_in[0];
    const float* verb_logits  = (const float*)d_in[1];
    const float* sub_boxes    = (const float*)d_in[2];
    const float* obj_boxes    = (const float*)d_in[3];
    const int*   target_sizes = (const int*)d_in[4];
    const float* cmat         = (const float*)d_in[5];

    float* out      = (float*)d_out;
    float* out_hoi  = out;
    float* out_lab  = out_hoi + (size_t)NBQ * NVERB;
    float* out_sb   = out_lab + NBQ;
    float* out_ob   = out_sb + (size_t)NBQ * 4;
    float* out_keep = out_ob + (size_t)NBQ * 4;

    // workspace layout
    char* w = (char*)d_ws;
    float*    ws_max = (float*)w;        w += (size_t)NBQ * 4;
    float*    sar    = (float*)w;        w += (size_t)NBQ * 4;
    float*    oar    = (float*)w;        w += (size_t)NBQ * 4;
    int*      ws_lab = (int*)w;          w += (size_t)NBQ * 4;
    int*      slab   = (int*)w;          w += (size_t)NBQ * 4;
    int*      ws_ord = (int*)w;          w += (size_t)NBQ * 4;
    unsigned* bmask  = (unsigned*)w;     w += (size_t)NCLS * 4 * 4;

    k0<<<(NCLS * 4 + 255) / 256, 256, 0, stream>>>(cmat, bmask);
    kA<<<NBQ / 16, 256, 0, stream>>>(obj_logits, verb_logits,
                                     sub_boxes, obj_boxes, target_sizes,
                                     (const uint4*)bmask,
                                     out_hoi, out_lab, out_sb, out_ob,
                                     ws_max, ws_lab, sar, oar);
    kB<<<dim3(NQ / 4, NB), 256, 0, stream>>>(ws_max, ws_lab, ws_ord, slab);
    kE<<<dim3((NLAB + 3) / 4, NB), 256, 0, stream>>>(out_sb, out_ob, sar, oar,
                                                     slab, ws_ord, out_keep);
}